// Round 1
// baseline (6389.377 us; speedup 1.0000x reference)
//
#include <hip/hip_runtime.h>
#include <math.h>

static constexpr int B_ = 512;
static constexpr int T_ = 16;
static constexpr int S_ = 64;
static constexpr int K_ = 32;
static constexpr int N_ = 1024;   // T_*S_
static constexpr int NPAD = 36;   // slab stride (floats), mult of 4, breaks bank conflicts

// ---------------- init: rowmap identity + logdet zero ----------------
__global__ void initk(int* __restrict__ rowmap, float* __restrict__ logdet) {
  int idx = blockIdx.x * 256 + threadIdx.x;
  if (idx < K_ * N_) rowmap[idx] = idx & (N_ - 1);
  if (idx < K_) logdet[idx] = 0.f;
}

// ---------------- build block-Toeplitz M[k][row][col] ----------------
// M[(i,a),(j,b)] = A[i-j,k,b,a] if i>=j else A[j-i,k,a,b]
__global__ __launch_bounds__(256) void buildM(const float* __restrict__ A, float* __restrict__ M) {
  size_t idx = (size_t)blockIdx.x * 256 + threadIdx.x;   // float4 index, total 8388608
  int k   = (int)(idx >> 18);          // / (N_*N_/4)
  int rem = (int)(idx & 262143);
  int row = rem >> 8;                  // / (N_/4)
  int c4  = (rem & 255) << 2;
  int i = row >> 6, a = row & 63;
  int j = c4 >> 6,  b0 = c4 & 63;
  float4 v;
  if (i >= j) {
    const float* Ad = A + ((size_t)((i - j) * K_ + k) << 12);
    v.x = Ad[(b0 + 0) * 64 + a];
    v.y = Ad[(b0 + 1) * 64 + a];
    v.z = Ad[(b0 + 2) * 64 + a];
    v.w = Ad[(b0 + 3) * 64 + a];
  } else {
    const float* Ad = A + ((size_t)((j - i) * K_ + k) << 12) + a * 64 + b0;
    v = *(const float4*)Ad;
  }
  *(float4*)(M + (idx << 2)) = v;
}

// ---------------- prep: r[k][j][s] and cterm[k] ----------------
// p[d] = A_d mu_k ; q[d] = A_d^T mu_k
// r[k][j] = 0.5(p0+q0) + sum_{d=1..15-j} p[d] + sum_{d=1..j} q[d]
// cterm[k] = 16*mu^T p0 + sum_{d>=1} 2*(16-d)*mu^T p[d]
__global__ __launch_bounds__(256) void prepk(const float* __restrict__ A, const float* __restrict__ mu,
                                             float* __restrict__ rbuf, float* __restrict__ cterm) {
  int k = blockIdx.x;
  __shared__ float smu[64];
  __shared__ float sp[1024], sq[1024];
  int tid = threadIdx.x;
  if (tid < 64) smu[tid] = mu[k * 64 + tid];
  __syncthreads();
  for (int idx = tid; idx < 1024; idx += 256) {
    int d = idx >> 6, s = idx & 63;
    const float* Ad = A + ((size_t)(d * K_ + k) << 12);
    float ap = 0.f, aq = 0.f;
    for (int s2 = 0; s2 < 64; ++s2) {
      ap += Ad[s * 64 + s2] * smu[s2];
      aq += Ad[s2 * 64 + s] * smu[s2];
    }
    sp[idx] = ap; sq[idx] = aq;
  }
  __syncthreads();
  for (int idx = tid; idx < 1024; idx += 256) {
    int j = idx >> 6, s = idx & 63;
    float acc = 0.5f * (sp[s] + sq[s]);
    for (int d = 1; d < 16; ++d) {
      if (d <= 15 - j) acc += sp[d * 64 + s];
      if (d <= j)      acc += sq[d * 64 + s];
    }
    rbuf[k * 1024 + idx] = acc;
  }
  if (tid < 64) {
    float a = 16.f * sp[tid];
    for (int d = 1; d < 16; ++d) a += 2.f * (float)(16 - d) * sp[d * 64 + tid];
    a *= smu[tid];
    for (int off = 32; off; off >>= 1) a += __shfl_xor(a, off);
    if (tid == 0) cterm[k] = a;
  }
}

// ---------------- Q kernel: Qp[g][b][k] partial quadratic forms ----------------
// x^T M x = sum_d w_d * <C_d[b], A[d,k]> ; C_d[a][v] = sum_j X[b,j,a]*X[b,j+d,v]
__global__ __launch_bounds__(256) void qkern(const float* __restrict__ X, const float* __restrict__ A,
                                             float* __restrict__ Qp) {
  int g = blockIdx.x;        // 0..3 -> d in {g, g+4, g+8, g+12}
  int btile = blockIdx.y;    // 0..127 -> 4 batches
  __shared__ float Xs[4][1024];
  __shared__ float Cs[4][4096];
  int tid = threadIdx.x;
  int wave = tid >> 6, lane = tid & 63;
  for (int t = tid; t < 4096; t += 256) {
    int bb = t >> 10, e = t & 1023;
    Xs[bb][e] = X[(size_t)(btile * 4 + bb) * 1024 + e];
  }
  float regQ[4][8];
#pragma unroll
  for (int bb = 0; bb < 4; ++bb)
#pragma unroll
    for (int kk = 0; kk < 8; ++kk) regQ[bb][kk] = 0.f;

  int a0 = (tid >> 4) << 2;
  int v0 = (tid & 15) << 2;
  for (int dd = 0; dd < 4; ++dd) {
    int d = g + (dd << 2);
    __syncthreads();
    // ---- build C_d for 4 batches, each thread a 4x4 tile ----
    for (int bb = 0; bb < 4; ++bb) {
      float4 r0 = {0,0,0,0}, r1 = {0,0,0,0}, r2 = {0,0,0,0}, r3 = {0,0,0,0};
      for (int j = 0; j + d < 16; ++j) {
        const float4 xa = *(const float4*)&Xs[bb][j * 64 + a0];
        const float4 xv = *(const float4*)&Xs[bb][(j + d) * 64 + v0];
        r0.x += xa.x * xv.x; r0.y += xa.x * xv.y; r0.z += xa.x * xv.z; r0.w += xa.x * xv.w;
        r1.x += xa.y * xv.x; r1.y += xa.y * xv.y; r1.z += xa.y * xv.z; r1.w += xa.y * xv.w;
        r2.x += xa.z * xv.x; r2.y += xa.z * xv.y; r2.z += xa.z * xv.z; r2.w += xa.z * xv.w;
        r3.x += xa.w * xv.x; r3.y += xa.w * xv.y; r3.z += xa.w * xv.z; r3.w += xa.w * xv.w;
      }
      *(float4*)&Cs[bb][(a0 + 0) * 64 + v0] = r0;
      *(float4*)&Cs[bb][(a0 + 1) * 64 + v0] = r1;
      *(float4*)&Cs[bb][(a0 + 2) * 64 + v0] = r2;
      *(float4*)&Cs[bb][(a0 + 3) * 64 + v0] = r3;
    }
    __syncthreads();
    // ---- dot with A[d,k] for 8 k's per wave, A loaded once per 4 batches ----
    float w = (d == 0) ? 1.f : 2.f;
    for (int ch = 0; ch < 16; ++ch) {
      int e4 = (ch * 64 + lane) << 2;
      float4 cv[4];
#pragma unroll
      for (int bb = 0; bb < 4; ++bb) {
        float4 t4 = *(const float4*)&Cs[bb][e4];
        cv[bb].x = w * t4.x; cv[bb].y = w * t4.y; cv[bb].z = w * t4.z; cv[bb].w = w * t4.w;
      }
#pragma unroll
      for (int kk = 0; kk < 8; ++kk) {
        int k = wave + (kk << 2);
        const float4 av = *(const float4*)(A + (((size_t)(d * K_ + k)) << 12) + e4);
#pragma unroll
        for (int bb = 0; bb < 4; ++bb)
          regQ[bb][kk] += av.x * cv[bb].x + av.y * cv[bb].y + av.z * cv[bb].z + av.w * cv[bb].w;
      }
    }
  }
#pragma unroll
  for (int bb = 0; bb < 4; ++bb)
#pragma unroll
    for (int kk = 0; kk < 8; ++kk) {
      float v = regQ[bb][kk];
      for (int off = 32; off; off >>= 1) v += __shfl_xor(v, off);
      regQ[bb][kk] = v;
    }
  if (lane == 0) {
    int b = btile * 4;
#pragma unroll
    for (int bb = 0; bb < 4; ++bb)
#pragma unroll
      for (int kk = 0; kk < 8; ++kk)
        Qp[((size_t)(g * B_ + b + bb) << 5) + (wave + (kk << 2))] = regQ[bb][kk];
  }
}

// ---------------- LU panel (nb=32), LDS slab, pivoting via rowmap ----------------
__global__ __launch_bounds__(256) void panelk(float* __restrict__ M, int* __restrict__ rowmap,
                                              float* __restrict__ logdet, int j0) {
  int k = blockIdx.x;
  float* Mk = M + ((size_t)k << 20);
  int* rmk = rowmap + (k << 10);
  int m = N_ - j0;
  __shared__ float slab[1024 * NPAD];
  __shared__ int smap[1024];
  __shared__ float redv[4];
  __shared__ int redi[4];
  __shared__ int spv;
  __shared__ float sinv_s;
  __shared__ float prow[32];
  __shared__ float slogdet;
  int tid = threadIdx.x;
  int lane = tid & 63, wv = tid >> 6;
  if (tid == 0) slogdet = 0.f;
  for (int i = tid; i < m; i += 256) smap[i] = rmk[j0 + i];
  __syncthreads();
  for (int t = tid; t < m * 8; t += 256) {
    int i = t >> 3, q = (t & 7) << 2;
    *(float4*)&slab[i * NPAD + q] = *(const float4*)&Mk[(size_t)smap[i] * N_ + j0 + q];
  }
  __syncthreads();

  int tx4 = (tid & 7) << 2;
  int ty  = tid >> 3;

  for (int jj = 0; jj < 32; ++jj) {
    // ---- pivot search over rows [jj, m) ----
    float bv = -1.f; int bi = jj;
    for (int i = jj + tid; i < m; i += 256) {
      float v = fabsf(slab[i * NPAD + jj]);
      if (v > bv) { bv = v; bi = i; }
    }
    for (int off = 32; off; off >>= 1) {
      float ov = __shfl_down(bv, off);
      int   oi = __shfl_down(bi, off);
      if (ov > bv) { bv = ov; bi = oi; }
    }
    if (lane == 0) { redv[wv] = bv; redi[wv] = bi; }
    __syncthreads();
    if (tid == 0) {
      float mv = redv[0]; int mi = redi[0];
      for (int w2 = 1; w2 < 4; ++w2) if (redv[w2] > mv) { mv = redv[w2]; mi = redi[w2]; }
      spv = mi;
    }
    __syncthreads();
    int p = spv;
    if (p != jj) {
      if (tid < 32) {
        float t1 = slab[jj * NPAD + tid];
        slab[jj * NPAD + tid] = slab[p * NPAD + tid];
        slab[p * NPAD + tid] = t1;
      } else if (tid == 32) {
        int t2 = smap[jj]; smap[jj] = smap[p]; smap[p] = t2;
      }
    }
    __syncthreads();
    if (tid == 0) {
      float dv = slab[jj * NPAD + jj];
      slogdet += logf(fabsf(dv));
      sinv_s = 1.0f / dv;
    }
    if (tid < 32) prow[tid] = (tid > jj) ? slab[jj * NPAD + tid] : 0.f;
    __syncthreads();
    float sinv = sinv_s;
    float4 pr4;
    pr4.x = prow[tx4 + 0]; pr4.y = prow[tx4 + 1]; pr4.z = prow[tx4 + 2]; pr4.w = prow[tx4 + 3];
    bool qa = (tx4 + 3) > jj;
    for (int i = jj + 1 + ty; i < m; i += 32) {
      float mult = slab[i * NPAD + jj] * sinv;
      if (qa) {
        float4* pp = (float4*)&slab[i * NPAD + tx4];
        float4 cur = *pp;
        cur.x -= mult * pr4.x; cur.y -= mult * pr4.y; cur.z -= mult * pr4.z; cur.w -= mult * pr4.w;
        *pp = cur;
      }
      if (tx4 == 0) slab[i * NPAD + jj] = mult;   // store multiplier (after quad RMW in program order)
    }
    __syncthreads();
  }

  for (int t = tid; t < m * 8; t += 256) {
    int i = t >> 3, q = (t & 7) << 2;
    *(float4*)&Mk[(size_t)smap[i] * N_ + j0 + q] = *(const float4*)&slab[i * NPAD + q];
  }
  for (int i = tid; i < m; i += 256) rmk[j0 + i] = smap[i];
  if (tid == 0) logdet[k] += slogdet;
}

// ---------------- TRSM: U12 = L11^{-1} A12 over trailing columns ----------------
__global__ __launch_bounds__(64) void trsmk(float* __restrict__ M, const int* __restrict__ rowmap, int j0) {
  int k = blockIdx.y;
  int c = j0 + 32 + (blockIdx.x << 6) + threadIdx.x;
  float* Mk = M + ((size_t)k << 20);
  __shared__ float l11[32 * 33];
  __shared__ int pr[32];
  int tid = threadIdx.x;
  if (tid < 32) pr[tid] = rowmap[(k << 10) + j0 + tid];
  __syncthreads();
  for (int t = tid; t < 1024; t += 64) {
    int rr = t >> 5, cc = t & 31;
    l11[rr * 33 + cc] = Mk[(size_t)pr[rr] * N_ + j0 + cc];
  }
  __syncthreads();
  if (c < N_) {
    float u[32];
#pragma unroll
    for (int rr = 0; rr < 32; ++rr) u[rr] = Mk[(size_t)pr[rr] * N_ + c];
#pragma unroll
    for (int rr = 1; rr < 32; ++rr)
#pragma unroll
      for (int t = 0; t < rr; ++t)
        u[rr] -= l11[rr * 33 + t] * u[t];
#pragma unroll
    for (int rr = 0; rr < 32; ++rr) Mk[(size_t)pr[rr] * N_ + c] = u[rr];
  }
}

// ---------------- trailing GEMM update: C -= L21 * U12 (rowmap-indirect rows) ----------------
__global__ __launch_bounds__(256) void gemmk(float* __restrict__ M, const int* __restrict__ rowmap, int j0) {
  int k = blockIdx.z;
  int t0 = j0 + 32;
  int r0 = t0 + (blockIdx.y << 6);
  int c0 = t0 + (blockIdx.x << 6);
  float* Mk = M + ((size_t)k << 20);
  const int* rmk = rowmap + (k << 10);
  __shared__ float LtT[32 * 68];
  __shared__ float Ut[32 * 68];
  __shared__ int rowL[64];
  __shared__ int prU[32];
  int tid = threadIdx.x;
  if (tid < 64) rowL[tid] = (r0 + tid < N_) ? rmk[r0 + tid] : -1;
  else if (tid < 96) prU[tid - 64] = rmk[j0 + (tid - 64)];
  __syncthreads();
  for (int x = tid; x < 2048; x += 256) {
    int r = x >> 5, t = x & 31;
    int pr = rowL[r];
    LtT[t * 68 + r] = (pr >= 0) ? Mk[(size_t)pr * N_ + j0 + t] : 0.f;
  }
  for (int x = tid; x < 2048; x += 256) {
    int t = x >> 6, c = x & 63;
    Ut[t * 68 + c] = (c0 + c < N_) ? Mk[(size_t)prU[t] * N_ + c0 + c] : 0.f;
  }
  __syncthreads();
  int tx = tid & 15, ty = tid >> 4;
  float4 acc0 = {0,0,0,0}, acc1 = {0,0,0,0}, acc2 = {0,0,0,0}, acc3 = {0,0,0,0};
#pragma unroll
  for (int t = 0; t < 32; ++t) {
    const float4 a4 = *(const float4*)&LtT[t * 68 + (ty << 2)];
    const float4 b4 = *(const float4*)&Ut[t * 68 + (tx << 2)];
    acc0.x += a4.x * b4.x; acc0.y += a4.x * b4.y; acc0.z += a4.x * b4.z; acc0.w += a4.x * b4.w;
    acc1.x += a4.y * b4.x; acc1.y += a4.y * b4.y; acc1.z += a4.y * b4.z; acc1.w += a4.y * b4.w;
    acc2.x += a4.z * b4.x; acc2.y += a4.z * b4.y; acc2.z += a4.z * b4.z; acc2.w += a4.z * b4.w;
    acc3.x += a4.w * b4.x; acc3.y += a4.w * b4.y; acc3.z += a4.w * b4.z; acc3.w += a4.w * b4.w;
  }
  int cc = c0 + (tx << 2);
  if (cc < N_) {
#pragma unroll
    for (int i2 = 0; i2 < 4; ++i2) {
      int rv = r0 + (ty << 2) + i2;
      if (rv < N_) {
        int pr = rowL[(ty << 2) + i2];
        float4* p = (float4*)&Mk[(size_t)pr * N_ + cc];
        float4 cur = *p;
        const float4 av = (i2 == 0) ? acc0 : (i2 == 1) ? acc1 : (i2 == 2) ? acc2 : acc3;
        cur.x -= av.x; cur.y -= av.y; cur.z -= av.z; cur.w -= av.w;
        *p = cur;
      }
    }
  }
}

// ---------------- final: L-term, lle, softmax ----------------
__global__ __launch_bounds__(256) void finalk(const float* __restrict__ X, const float* __restrict__ rbuf,
                                              const float* __restrict__ cterm, const float* __restrict__ logdet,
                                              const float* __restrict__ Qp, float* __restrict__ out) {
  int b = blockIdx.x;
  __shared__ float Xs[1024];
  __shared__ float lleS[32];
  int tid = threadIdx.x, wave = tid >> 6, lane = tid & 63;
  for (int i = tid; i < 1024; i += 256) Xs[i] = X[(size_t)b * 1024 + i];
  __syncthreads();
#pragma unroll
  for (int kk = 0; kk < 8; ++kk) {
    int k = wave + (kk << 2);
    const float* rk = rbuf + (size_t)k * 1024;
    float acc = 0.f;
#pragma unroll
    for (int ch = 0; ch < 4; ++ch) {
      int e4 = (ch * 64 + lane) << 2;
      const float4 rv = *(const float4*)(rk + e4);
      const float4 xv = *(const float4*)&Xs[e4];
      acc += rv.x * xv.x + rv.y * xv.y + rv.z * xv.z + rv.w * xv.w;
    }
    for (int off = 32; off; off >>= 1) acc += __shfl_xor(acc, off);
    if (lane == 0) {
      float Qv = 0.f;
#pragma unroll
      for (int g = 0; g < 4; ++g) Qv += Qp[((size_t)(g * B_ + b) << 5) + k];
      float P1 = Qv - 2.f * acc + cterm[k];
      lleS[k] = -0.5f * P1 + logdet[k];
    }
  }
  __syncthreads();
  if (wave == 0) {
    float v = lleS[lane & 31];
    float mx = v;
    for (int off = 16; off; off >>= 1) mx = fmaxf(mx, __shfl_xor(mx, off));
    float e = expf(v - mx);
    float s = e;
    for (int off = 16; off; off >>= 1) s += __shfl_xor(s, off);
    if (lane < 32) out[b * 32 + lane] = e / s;
  }
}

extern "C" void kernel_launch(void* const* d_in, const int* in_sizes, int n_in,
                              void* d_out, int out_size, void* d_ws, size_t ws_size,
                              hipStream_t stream) {
  const float* X  = (const float*)d_in[0];
  const float* mu = (const float*)d_in[1];
  const float* A  = (const float*)d_in[2];
  float* out = (float*)d_out;
  float* ws  = (float*)d_ws;

  if (ws_size < 134742272ull) {   // need ~128.5 MB of scratch
    hipMemsetAsync(d_out, 0, (size_t)out_size * sizeof(float), stream);
    return;
  }

  float* M      = ws;                        // 33554432 floats
  int*   rowmap = (int*)(ws + 33554432);     // 32768 ints
  float* logdet = ws + 33587200;             // 32
  float* rbuf   = ws + 33587232;             // 32768
  float* cterm  = ws + 33620000;             // 32
  float* Qp     = ws + 33620032;             // 65536

  initk<<<dim3(128), dim3(256), 0, stream>>>(rowmap, logdet);
  buildM<<<dim3(32768), dim3(256), 0, stream>>>(A, M);
  prepk<<<dim3(32), dim3(256), 0, stream>>>(A, mu, rbuf, cterm);
  qkern<<<dim3(4, 128), dim3(256), 0, stream>>>(X, A, Qp);

  for (int s = 0; s < 32; ++s) {
    int j0 = s * 32;
    panelk<<<dim3(32), dim3(256), 0, stream>>>(M, rowmap, logdet, j0);
    int m = N_ - j0 - 32;
    if (m > 0) {
      int mt = (m + 63) >> 6;
      trsmk<<<dim3(mt, 32), dim3(64), 0, stream>>>(M, rowmap, j0);
      gemmk<<<dim3(mt, mt, 32), dim3(256), 0, stream>>>(M, rowmap, j0);
    }
  }

  finalk<<<dim3(512), dim3(256), 0, stream>>>(X, rbuf, cterm, logdet, Qp, out);
}

// Round 2
// 5332.491 us; speedup vs baseline: 1.1982x; 1.1982x over previous
//
#include <hip/hip_runtime.h>
#include <math.h>

static constexpr int B_ = 512;
static constexpr int T_ = 16;
static constexpr int S_ = 64;
static constexpr int K_ = 32;
static constexpr int N_ = 1024;   // T_*S_
static constexpr int NPAD = 36;   // slab stride (floats)

// ---------------- init: rowmap identity + logdet zero ----------------
__global__ void initk(int* __restrict__ rowmap, float* __restrict__ logdet) {
  int idx = blockIdx.x * 256 + threadIdx.x;
  if (idx < K_ * N_) rowmap[idx] = idx & (N_ - 1);
  if (idx < K_) logdet[idx] = 0.f;
}

// ---------------- build block-Toeplitz M[k][row][col] ----------------
// M[(i,a),(j,b)] = A[i-j,k,b,a] if i >= j else A[j-i,k,a,b]
__global__ __launch_bounds__(256) void buildM(const float* __restrict__ A, float* __restrict__ M) {
  size_t idx = (size_t)blockIdx.x * 256 + threadIdx.x;   // float4 index, total 8388608
  int k   = (int)(idx >> 18);
  int rem = (int)(idx & 262143);
  int row = rem >> 8;
  int c4  = (rem & 255) << 2;
  int i = row >> 6, a = row & 63;
  int j = c4 >> 6,  b0 = c4 & 63;
  float4 v;
  if (i >= j) {
    const float* Ad = A + ((size_t)((i - j) * K_ + k) << 12);
    v.x = Ad[(b0 + 0) * 64 + a];
    v.y = Ad[(b0 + 1) * 64 + a];
    v.z = Ad[(b0 + 2) * 64 + a];
    v.w = Ad[(b0 + 3) * 64 + a];
  } else {
    const float* Ad = A + ((size_t)((j - i) * K_ + k) << 12) + a * 64 + b0;
    v = *(const float4*)Ad;
  }
  *(float4*)(M + (idx << 2)) = v;
}

// ---------------- prep: r[k][j][s] and cterm[k] ----------------
__global__ __launch_bounds__(256) void prepk(const float* __restrict__ A, const float* __restrict__ mu,
                                             float* __restrict__ rbuf, float* __restrict__ cterm) {
  int k = blockIdx.x;
  __shared__ float smu[64];
  __shared__ float sp[1024], sq[1024];
  int tid = threadIdx.x;
  if (tid < 64) smu[tid] = mu[k * 64 + tid];
  __syncthreads();
  for (int idx = tid; idx < 1024; idx += 256) {
    int d = idx >> 6, s = idx & 63;
    const float* Ad = A + ((size_t)(d * K_ + k) << 12);
    float ap = 0.f, aq = 0.f;
    for (int s2 = 0; s2 < 64; ++s2) {
      ap += Ad[s * 64 + s2] * smu[s2];
      aq += Ad[s2 * 64 + s] * smu[s2];
    }
    sp[idx] = ap; sq[idx] = aq;
  }
  __syncthreads();
  for (int idx = tid; idx < 1024; idx += 256) {
    int j = idx >> 6, s = idx & 63;
    float acc = 0.5f * (sp[s] + sq[s]);
    for (int d = 1; d < 16; ++d) {
      if (d <= 15 - j) acc += sp[d * 64 + s];
      if (d <= j)      acc += sq[d * 64 + s];
    }
    rbuf[k * 1024 + idx] = acc;
  }
  if (tid < 64) {
    float a = 16.f * sp[tid];
    for (int d = 1; d < 16; ++d) a += 2.f * (float)(16 - d) * sp[d * 64 + tid];
    a *= smu[tid];
    for (int off = 32; off; off >>= 1) a += __shfl_xor(a, off);
    if (tid == 0) cterm[k] = a;
  }
}

// ---------------- Q kernel: Qp[g][b][k] partial quadratic forms ----------------
__global__ __launch_bounds__(256) void qkern(const float* __restrict__ X, const float* __restrict__ A,
                                             float* __restrict__ Qp) {
  int g = blockIdx.x;        // d in {g, g+4, g+8, g+12}
  int btile = blockIdx.y;    // 4 batches each
  __shared__ float Xs[4][1024];
  __shared__ float Cs[4][4096];
  int tid = threadIdx.x;
  int wave = tid >> 6, lane = tid & 63;
  for (int t = tid; t < 4096; t += 256) {
    int bb = t >> 10, e = t & 1023;
    Xs[bb][e] = X[(size_t)(btile * 4 + bb) * 1024 + e];
  }
  float regQ[4][8];
#pragma unroll
  for (int bb = 0; bb < 4; ++bb)
#pragma unroll
    for (int kk = 0; kk < 8; ++kk) regQ[bb][kk] = 0.f;

  int a0 = (tid >> 4) << 2;
  int v0 = (tid & 15) << 2;
  for (int dd = 0; dd < 4; ++dd) {
    int d = g + (dd << 2);
    __syncthreads();
    for (int bb = 0; bb < 4; ++bb) {
      float4 r0 = {0,0,0,0}, r1 = {0,0,0,0}, r2 = {0,0,0,0}, r3 = {0,0,0,0};
      for (int j = 0; j + d < 16; ++j) {
        const float4 xa = *(const float4*)&Xs[bb][j * 64 + a0];
        const float4 xv = *(const float4*)&Xs[bb][(j + d) * 64 + v0];
        r0.x += xa.x * xv.x; r0.y += xa.x * xv.y; r0.z += xa.x * xv.z; r0.w += xa.x * xv.w;
        r1.x += xa.y * xv.x; r1.y += xa.y * xv.y; r1.z += xa.y * xv.z; r1.w += xa.y * xv.w;
        r2.x += xa.z * xv.x; r2.y += xa.z * xv.y; r2.z += xa.z * xv.z; r2.w += xa.z * xv.w;
        r3.x += xa.w * xv.x; r3.y += xa.w * xv.y; r3.z += xa.w * xv.z; r3.w += xa.w * xv.w;
      }
      *(float4*)&Cs[bb][(a0 + 0) * 64 + v0] = r0;
      *(float4*)&Cs[bb][(a0 + 1) * 64 + v0] = r1;
      *(float4*)&Cs[bb][(a0 + 2) * 64 + v0] = r2;
      *(float4*)&Cs[bb][(a0 + 3) * 64 + v0] = r3;
    }
    __syncthreads();
    float w = (d == 0) ? 1.f : 2.f;
    for (int ch = 0; ch < 16; ++ch) {
      int e4 = (ch * 64 + lane) << 2;
      float4 cv[4];
#pragma unroll
      for (int bb = 0; bb < 4; ++bb) {
        float4 t4 = *(const float4*)&Cs[bb][e4];
        cv[bb].x = w * t4.x; cv[bb].y = w * t4.y; cv[bb].z = w * t4.z; cv[bb].w = w * t4.w;
      }
#pragma unroll
      for (int kk = 0; kk < 8; ++kk) {
        int k = wave + (kk << 2);
        const float4 av = *(const float4*)(A + (((size_t)(d * K_ + k)) << 12) + e4);
#pragma unroll
        for (int bb = 0; bb < 4; ++bb)
          regQ[bb][kk] += av.x * cv[bb].x + av.y * cv[bb].y + av.z * cv[bb].z + av.w * cv[bb].w;
      }
    }
  }
#pragma unroll
  for (int bb = 0; bb < 4; ++bb)
#pragma unroll
    for (int kk = 0; kk < 8; ++kk) {
      float v = regQ[bb][kk];
      for (int off = 32; off; off >>= 1) v += __shfl_xor(v, off);
      regQ[bb][kk] = v;
    }
  if (lane == 0) {
    int b = btile * 4;
#pragma unroll
    for (int bb = 0; bb < 4; ++bb)
#pragma unroll
      for (int kk = 0; kk < 8; ++kk)
        Qp[((size_t)(g * B_ + b + bb) << 5) + (wave + (kk << 2))] = regQ[bb][kk];
  }
}

// ---------------- LU panel (nb=32) v2: merged scan, L exported to dead column block ----------------
__global__ __launch_bounds__(256) void panelk(float* __restrict__ M, int* __restrict__ rowmap,
                                              float* __restrict__ logdet, int j0) {
  int k = blockIdx.x;
  float* Mk = M + ((size_t)k << 20);
  int* rmk = rowmap + (k << 10);
  int m = N_ - j0;
  __shared__ float slab[1024 * NPAD];
  __shared__ int smap[1024];
  __shared__ float candv[32];
  __shared__ int candi[32];
  __shared__ float pivval[32];
  __shared__ float ssinv;
  int tid = threadIdx.x;
  int lane = tid & 63;

  for (int i = tid; i < m; i += 256) smap[i] = rmk[j0 + i];
  __syncthreads();
  for (int t = tid; t < m * 8; t += 256) {
    int i = t >> 3, q = (t & 7) << 2;
    *(float4*)&slab[i * NPAD + q] = *(const float4*)&Mk[(size_t)smap[i] * N_ + j0 + q];
  }
  __syncthreads();

  // initial pivot scan of column 0 -> candv[0..31]
  {
    float bv = -1.f; int bi = 0;
    for (int i = tid; i < m; i += 256) {
      float v = fabsf(slab[i * NPAD]);
      if (v > bv) { bv = v; bi = i; }
    }
    for (int off = 4; off; off >>= 1) {
      float ov = __shfl_down(bv, off, 8);
      int   oi = __shfl_down(bi, off, 8);
      if (ov > bv) { bv = ov; bi = oi; }
    }
    if ((tid & 7) == 0) { candv[tid >> 3] = bv; candi[tid >> 3] = bi; }
  }
  __syncthreads();

  int ty = tid >> 3, txg = tid & 7;
  int cb = txg << 2;

  for (int jj = 0; jj < 32; ++jj) {
    // ---- wave 0: pivot select + swap ----
    if (tid < 64) {
      float cv = (lane < 32) ? candv[lane] : -1.f;
      int ci = (lane < 32) ? candi[lane] : jj;
      for (int off = 16; off; off >>= 1) {
        float ov = __shfl_down(cv, off, 32);
        int oi = __shfl_down(ci, off, 32);
        if (ov > cv) { cv = ov; ci = oi; }
      }
      int p = __shfl(ci, 0);
      float dv = slab[p * NPAD + jj];
      if (lane == 0) { pivval[jj] = dv; ssinv = 1.f / dv; }
      if (p != jj) {
        if (lane < 32) {
          float t1 = slab[jj * NPAD + lane];
          slab[jj * NPAD + lane] = slab[p * NPAD + lane];
          slab[p * NPAD + lane] = t1;
        } else if (lane == 32) {
          int t2 = smap[jj]; smap[jj] = smap[p]; smap[p] = t2;
        }
      }
    }
    __syncthreads();

    // ---- update rows jj+1.. and merged scan of column jj+1 ----
    int jn = jj + 1;
    int gn = jn >> 2, subn = jn & 3;
    bool doScan = (jn < 32) && (txg == gn);
    bool active = (cb + 3) >= jj;
    float sinv = ssinv;
    float4 pr4, pm;
    pr4.x = slab[jj * NPAD + cb + 0];
    pr4.y = slab[jj * NPAD + cb + 1];
    pr4.z = slab[jj * NPAD + cb + 2];
    pr4.w = slab[jj * NPAD + cb + 3];
    pm.x = (cb + 0 > jj) ? pr4.x : 0.f;
    pm.y = (cb + 1 > jj) ? pr4.y : 0.f;
    pm.z = (cb + 2 > jj) ? pr4.z : 0.f;
    pm.w = (cb + 3 > jj) ? pr4.w : 0.f;
    bool m0 = (cb + 0 == jj), m1 = (cb + 1 == jj), m2 = (cb + 2 == jj), m3 = (cb + 3 == jj);
    float nbv = -1.f; int nbi = jn;
    if (active) {
      for (int i = jn + ty; i < m; i += 32) {
        float mult = slab[i * NPAD + jj] * sinv;   // read before any store in this wave (lockstep)
        float4* pp = (float4*)&slab[i * NPAD + cb];
        float4 cur = *pp;
        cur.x = m0 ? mult : cur.x - mult * pm.x;
        cur.y = m1 ? mult : cur.y - mult * pm.y;
        cur.z = m2 ? mult : cur.z - mult * pm.z;
        cur.w = m3 ? mult : cur.w - mult * pm.w;
        *pp = cur;
        if (doScan) {
          float nv = subn == 0 ? cur.x : subn == 1 ? cur.y : subn == 2 ? cur.z : cur.w;
          nv = fabsf(nv);
          if (nv > nbv) { nbv = nv; nbi = i; }
        }
      }
    }
    if (doScan) { candv[ty] = nbv; candi[ty] = nbi; }
    __syncthreads();
  }

  // logdet from pivots
  if (tid < 32) {
    float lv = logf(fabsf(pivval[tid]));
    for (int off = 16; off; off >>= 1) lv += __shfl_down(lv, off, 32);
    if (tid == 0) logdet[k] += lv;
  }
  // export L (pivoted order) into dead column block M[j0+i][j0..j0+32)
  for (int t = tid; t < m * 8; t += 256) {
    int i = t >> 3, q = (t & 7) << 2;
    *(float4*)&Mk[(size_t)(j0 + i) * N_ + j0 + q] = *(const float4*)&slab[i * NPAD + q];
  }
  for (int i = tid; i < m; i += 256) rmk[j0 + i] = smap[i];
}

// ---------------- fused TRSM + trailing GEMM update, 128x128 C tile ----------------
__global__ __launch_bounds__(256) void updatek(float* __restrict__ M, const int* __restrict__ rowmap, int j0) {
  int k = blockIdx.z;
  int mprime = N_ - j0 - 32;
  int r0 = blockIdx.y << 7;
  int c0 = blockIdx.x << 7;
  float* Mk = M + ((size_t)k << 20);
  const int* rmk = rowmap + (k << 10);
  __shared__ float l11[32 * 36];
  __shared__ float LtT[32 * 132];
  __shared__ float Ut[32 * 132];
  __shared__ int rowL[128];
  __shared__ int prU[32];
  int tid = threadIdx.x;

  if (tid < 128) rowL[tid] = (r0 + tid < mprime) ? rmk[j0 + 32 + r0 + tid] : -1;
  else if (tid < 160) prU[tid - 128] = rmk[j0 + (tid - 128)];
  {
    int rr = tid >> 3, q = (tid & 7) << 2;
    *(float4*)&l11[rr * 36 + q] = *(const float4*)(Mk + (size_t)(j0 + rr) * N_ + j0 + q);
  }
  for (int x = tid; x < 1024; x += 256) {
    int i = x >> 3, q = (x & 7) << 2;
    float4 v = {0.f, 0.f, 0.f, 0.f};
    if (r0 + i < mprime) v = *(const float4*)(Mk + (size_t)(j0 + 32 + r0 + i) * N_ + j0 + q);
    LtT[(q + 0) * 132 + i] = v.x;
    LtT[(q + 1) * 132 + i] = v.y;
    LtT[(q + 2) * 132 + i] = v.z;
    LtT[(q + 3) * 132 + i] = v.w;
  }
  __syncthreads();

  // TRSM: threads 0..127 each own one column of the 32x128 U12 tile
  if (tid < 128) {
    int c = c0 + tid;
    bool ok = (c < mprime);
    float u[32];
#pragma unroll
    for (int rr = 0; rr < 32; ++rr) {
      float av = ok ? Mk[(size_t)prU[rr] * N_ + j0 + 32 + c] : 0.f;
#pragma unroll
      for (int t = 0; t < rr; ++t) av -= l11[rr * 36 + t] * u[t];
      u[rr] = av;
      Ut[rr * 132 + tid] = av;
    }
  }
  __syncthreads();

  // GEMM: 128x128 tile, 8x8 per thread in 2x2 blocks of 4x4
  int tx = tid & 15, ty = tid >> 4;
  float4 acc[2][2][4];
#pragma unroll
  for (int a = 0; a < 2; ++a)
#pragma unroll
    for (int b = 0; b < 2; ++b)
#pragma unroll
      for (int r = 0; r < 4; ++r) acc[a][b][r] = make_float4(0.f, 0.f, 0.f, 0.f);

#pragma unroll 8
  for (int t = 0; t < 32; ++t) {
    float4 aL = *(const float4*)&LtT[t * 132 + (ty << 2)];
    float4 aH = *(const float4*)&LtT[t * 132 + (ty << 2) + 64];
    float4 bL = *(const float4*)&Ut[t * 132 + (tx << 2)];
    float4 bH = *(const float4*)&Ut[t * 132 + (tx << 2) + 64];
#define FMA4(dst, s, b4) dst.x += (s) * b4.x; dst.y += (s) * b4.y; dst.z += (s) * b4.z; dst.w += (s) * b4.w;
    FMA4(acc[0][0][0], aL.x, bL) FMA4(acc[0][0][1], aL.y, bL) FMA4(acc[0][0][2], aL.z, bL) FMA4(acc[0][0][3], aL.w, bL)
    FMA4(acc[0][1][0], aL.x, bH) FMA4(acc[0][1][1], aL.y, bH) FMA4(acc[0][1][2], aL.z, bH) FMA4(acc[0][1][3], aL.w, bH)
    FMA4(acc[1][0][0], aH.x, bL) FMA4(acc[1][0][1], aH.y, bL) FMA4(acc[1][0][2], aH.z, bL) FMA4(acc[1][0][3], aH.w, bL)
    FMA4(acc[1][1][0], aH.x, bH) FMA4(acc[1][1][1], aH.y, bH) FMA4(acc[1][1][2], aH.z, bH) FMA4(acc[1][1][3], aH.w, bH)
#undef FMA4
  }

#pragma unroll
  for (int ri = 0; ri < 2; ++ri)
#pragma unroll
    for (int r = 0; r < 4; ++r) {
      int lr = (ty << 2) + r + (ri << 6);
      int pr = rowL[lr];
      if (pr < 0) continue;
      float* rowp = Mk + (size_t)pr * N_ + j0 + 32 + c0;
#pragma unroll
      for (int ci = 0; ci < 2; ++ci) {
        int lc = (tx << 2) + (ci << 6);
        if (c0 + lc < mprime) {
          float4* p = (float4*)(rowp + lc);
          float4 cur = *p;
          cur.x -= acc[ri][ci][r].x;
          cur.y -= acc[ri][ci][r].y;
          cur.z -= acc[ri][ci][r].z;
          cur.w -= acc[ri][ci][r].w;
          *p = cur;
        }
      }
    }
}

// ---------------- final: cross term, lle, softmax ----------------
__global__ __launch_bounds__(256) void finalk(const float* __restrict__ X, const float* __restrict__ rbuf,
                                              const float* __restrict__ cterm, const float* __restrict__ logdet,
                                              const float* __restrict__ Qp, float* __restrict__ out) {
  int b = blockIdx.x;
  __shared__ float Xs[1024];
  __shared__ float lleS[32];
  int tid = threadIdx.x, wave = tid >> 6, lane = tid & 63;
  for (int i = tid; i < 1024; i += 256) Xs[i] = X[(size_t)b * 1024 + i];
  __syncthreads();
#pragma unroll
  for (int kk = 0; kk < 8; ++kk) {
    int k = wave + (kk << 2);
    const float* rk = rbuf + (size_t)k * 1024;
    float acc = 0.f;
#pragma unroll
    for (int ch = 0; ch < 4; ++ch) {
      int e4 = (ch * 64 + lane) << 2;
      const float4 rv = *(const float4*)(rk + e4);
      const float4 xv = *(const float4*)&Xs[e4];
      acc += rv.x * xv.x + rv.y * xv.y + rv.z * xv.z + rv.w * xv.w;
    }
    for (int off = 32; off; off >>= 1) acc += __shfl_xor(acc, off);
    if (lane == 0) {
      float Qv = 0.f;
#pragma unroll
      for (int g = 0; g < 4; ++g) Qv += Qp[((size_t)(g * B_ + b) << 5) + k];
      float P1 = Qv - 2.f * acc + cterm[k];
      lleS[k] = -0.5f * P1 + logdet[k];
    }
  }
  __syncthreads();
  if (wave == 0) {
    float v = lleS[lane & 31];
    float mx = v;
    for (int off = 16; off; off >>= 1) mx = fmaxf(mx, __shfl_xor(mx, off));
    float e = expf(v - mx);
    float s = e;
    for (int off = 16; off; off >>= 1) s += __shfl_xor(s, off);
    if (lane < 32) out[b * 32 + lane] = e / s;
  }
}

extern "C" void kernel_launch(void* const* d_in, const int* in_sizes, int n_in,
                              void* d_out, int out_size, void* d_ws, size_t ws_size,
                              hipStream_t stream) {
  const float* X  = (const float*)d_in[0];
  const float* mu = (const float*)d_in[1];
  const float* A  = (const float*)d_in[2];
  float* out = (float*)d_out;
  float* ws  = (float*)d_ws;

  if (ws_size < 134742272ull) {
    hipMemsetAsync(d_out, 0, (size_t)out_size * sizeof(float), stream);
    return;
  }

  float* M      = ws;                        // 33554432 floats (128 MB)
  int*   rowmap = (int*)(ws + 33554432);     // 32768 ints
  float* logdet = ws + 33587200;             // 32
  float* rbuf   = ws + 33587232;             // 32768
  float* cterm  = ws + 33620000;             // 32
  float* Qp     = ws + 33620032;             // 65536

  initk<<<dim3(128), dim3(256), 0, stream>>>(rowmap, logdet);
  buildM<<<dim3(32768), dim3(256), 0, stream>>>(A, M);
  prepk<<<dim3(32), dim3(256), 0, stream>>>(A, mu, rbuf, cterm);
  qkern<<<dim3(4, 128), dim3(256), 0, stream>>>(X, A, Qp);

  for (int s = 0; s < 32; ++s) {
    int j0 = s * 32;
    panelk<<<dim3(32), dim3(256), 0, stream>>>(M, rowmap, logdet, j0);
    int mprime = N_ - j0 - 32;
    if (mprime > 0) {
      int mt = (mprime + 127) >> 7;
      updatek<<<dim3(mt, mt, 32), dim3(256), 0, stream>>>(M, rowmap, j0);
    }
  }

  finalk<<<dim3(512), dim3(256), 0, stream>>>(X, rbuf, cterm, logdet, Qp, out);
}

// Round 3
// 3005.674 us; speedup vs baseline: 2.1258x; 1.7741x over previous
//
#include <hip/hip_runtime.h>
#include <math.h>

static constexpr int B_ = 512;
static constexpr int T_ = 16;
static constexpr int S_ = 64;
static constexpr int K_ = 32;
static constexpr int N_ = 1024;   // T_*S_

// ---------------- init: rowmap identity + logdet zero ----------------
__global__ void initk(int* __restrict__ rowmap, float* __restrict__ logdet) {
  int idx = blockIdx.x * 256 + threadIdx.x;
  if (idx < K_ * N_) rowmap[idx] = idx & (N_ - 1);
  if (idx < K_) logdet[idx] = 0.f;
}

// ---------------- build block-Toeplitz M[k][row][col] ----------------
// M[(i,a),(j,b)] = A[i-j,k,b,a] if i >= j else A[j-i,k,a,b]
__global__ __launch_bounds__(256) void buildM(const float* __restrict__ A, float* __restrict__ M) {
  size_t idx = (size_t)blockIdx.x * 256 + threadIdx.x;   // float4 index, total 8388608
  int k   = (int)(idx >> 18);
  int rem = (int)(idx & 262143);
  int row = rem >> 8;
  int c4  = (rem & 255) << 2;
  int i = row >> 6, a = row & 63;
  int j = c4 >> 6,  b0 = c4 & 63;
  float4 v;
  if (i >= j) {
    const float* Ad = A + ((size_t)((i - j) * K_ + k) << 12);
    v.x = Ad[(b0 + 0) * 64 + a];
    v.y = Ad[(b0 + 1) * 64 + a];
    v.z = Ad[(b0 + 2) * 64 + a];
    v.w = Ad[(b0 + 3) * 64 + a];
  } else {
    const float* Ad = A + ((size_t)((j - i) * K_ + k) << 12) + a * 64 + b0;
    v = *(const float4*)Ad;
  }
  *(float4*)(M + (idx << 2)) = v;
}

// ---------------- prep: r[k][j][s] and cterm[k] ----------------
__global__ __launch_bounds__(256) void prepk(const float* __restrict__ A, const float* __restrict__ mu,
                                             float* __restrict__ rbuf, float* __restrict__ cterm) {
  int k = blockIdx.x;
  __shared__ float smu[64];
  __shared__ float sp[1024], sq[1024];
  int tid = threadIdx.x;
  if (tid < 64) smu[tid] = mu[k * 64 + tid];
  __syncthreads();
  for (int idx = tid; idx < 1024; idx += 256) {
    int d = idx >> 6, s = idx & 63;
    const float* Ad = A + ((size_t)(d * K_ + k) << 12);
    float ap = 0.f, aq = 0.f;
    for (int s2 = 0; s2 < 64; ++s2) {
      ap += Ad[s * 64 + s2] * smu[s2];
      aq += Ad[s2 * 64 + s] * smu[s2];
    }
    sp[idx] = ap; sq[idx] = aq;
  }
  __syncthreads();
  for (int idx = tid; idx < 1024; idx += 256) {
    int j = idx >> 6, s = idx & 63;
    float acc = 0.5f * (sp[s] + sq[s]);
    for (int d = 1; d < 16; ++d) {
      if (d <= 15 - j) acc += sp[d * 64 + s];
      if (d <= j)      acc += sq[d * 64 + s];
    }
    rbuf[k * 1024 + idx] = acc;
  }
  if (tid < 64) {
    float a = 16.f * sp[tid];
    for (int d = 1; d < 16; ++d) a += 2.f * (float)(16 - d) * sp[d * 64 + tid];
    a *= smu[tid];
    for (int off = 32; off; off >>= 1) a += __shfl_xor(a, off);
    if (tid == 0) cterm[k] = a;
  }
}

// ---------------- Q kernel: Qp[g][b][k] partial quadratic forms ----------------
__global__ __launch_bounds__(256) void qkern(const float* __restrict__ X, const float* __restrict__ A,
                                             float* __restrict__ Qp) {
  int g = blockIdx.x;        // d in {g, g+4, g+8, g+12}
  int btile = blockIdx.y;    // 4 batches each
  __shared__ float Xs[4][1024];
  __shared__ float Cs[4][4096];
  int tid = threadIdx.x;
  int wave = tid >> 6, lane = tid & 63;
  for (int t = tid; t < 4096; t += 256) {
    int bb = t >> 10, e = t & 1023;
    Xs[bb][e] = X[(size_t)(btile * 4 + bb) * 1024 + e];
  }
  float regQ[4][8];
#pragma unroll
  for (int bb = 0; bb < 4; ++bb)
#pragma unroll
    for (int kk = 0; kk < 8; ++kk) regQ[bb][kk] = 0.f;

  int a0 = (tid >> 4) << 2;
  int v0 = (tid & 15) << 2;
  for (int dd = 0; dd < 4; ++dd) {
    int d = g + (dd << 2);
    __syncthreads();
    for (int bb = 0; bb < 4; ++bb) {
      float4 r0 = {0,0,0,0}, r1 = {0,0,0,0}, r2 = {0,0,0,0}, r3 = {0,0,0,0};
      for (int j = 0; j + d < 16; ++j) {
        const float4 xa = *(const float4*)&Xs[bb][j * 64 + a0];
        const float4 xv = *(const float4*)&Xs[bb][(j + d) * 64 + v0];
        r0.x += xa.x * xv.x; r0.y += xa.x * xv.y; r0.z += xa.x * xv.z; r0.w += xa.x * xv.w;
        r1.x += xa.y * xv.x; r1.y += xa.y * xv.y; r1.z += xa.y * xv.z; r1.w += xa.y * xv.w;
        r2.x += xa.z * xv.x; r2.y += xa.z * xv.y; r2.z += xa.z * xv.z; r2.w += xa.z * xv.w;
        r3.x += xa.w * xv.x; r3.y += xa.w * xv.y; r3.z += xa.w * xv.z; r3.w += xa.w * xv.w;
      }
      *(float4*)&Cs[bb][(a0 + 0) * 64 + v0] = r0;
      *(float4*)&Cs[bb][(a0 + 1) * 64 + v0] = r1;
      *(float4*)&Cs[bb][(a0 + 2) * 64 + v0] = r2;
      *(float4*)&Cs[bb][(a0 + 3) * 64 + v0] = r3;
    }
    __syncthreads();
    float w = (d == 0) ? 1.f : 2.f;
    for (int ch = 0; ch < 16; ++ch) {
      int e4 = (ch * 64 + lane) << 2;
      float4 cv[4];
#pragma unroll
      for (int bb = 0; bb < 4; ++bb) {
        float4 t4 = *(const float4*)&Cs[bb][e4];
        cv[bb].x = w * t4.x; cv[bb].y = w * t4.y; cv[bb].z = w * t4.z; cv[bb].w = w * t4.w;
      }
#pragma unroll
      for (int kk = 0; kk < 8; ++kk) {
        int k = wave + (kk << 2);
        const float4 av = *(const float4*)(A + (((size_t)(d * K_ + k)) << 12) + e4);
#pragma unroll
        for (int bb = 0; bb < 4; ++bb)
          regQ[bb][kk] += av.x * cv[bb].x + av.y * cv[bb].y + av.z * cv[bb].z + av.w * cv[bb].w;
      }
    }
  }
#pragma unroll
  for (int bb = 0; bb < 4; ++bb)
#pragma unroll
    for (int kk = 0; kk < 8; ++kk) {
      float v = regQ[bb][kk];
      for (int off = 32; off; off >>= 1) v += __shfl_xor(v, off);
      regQ[bb][kk] = v;
    }
  if (lane == 0) {
    int b = btile * 4;
#pragma unroll
    for (int bb = 0; bb < 4; ++bb)
#pragma unroll
      for (int kk = 0; kk < 8; ++kk)
        Qp[((size_t)(g * B_ + b + bb) << 5) + (wave + (kk << 2))] = regQ[bb][kk];
  }
}

// ---------------- LU panel (nb=32) v3: one thread per row, panel in registers ----------------
// Thread t owns logical row t of the panel (32 floats in VGPRs). Per step:
// shuffle-argmax pivot, stage pivot row in LDS (doubles as swap buffer + broadcast),
// 32 register FMAs. 3 barriers/step, zero LDS RMW traffic.
__global__ __launch_bounds__(1024) void panelk(float* __restrict__ M, int* __restrict__ rowmap,
                                               float* __restrict__ logdet, int j0) {
  int k = blockIdx.x;
  float* Mk = M + ((size_t)k << 20);
  int* rmk = rowmap + (k << 10);
  int m = N_ - j0;
  int t = threadIdx.x;
  int bdim = blockDim.x;
  int lane = t & 63, wid = t >> 6;
  int nw = (bdim + 63) >> 6;

  __shared__ float bufP[32];
  __shared__ float bufJ[32];
  __shared__ int origP, origJ;
  __shared__ float candv[16];
  __shared__ int candi[16];
  __shared__ int spiv;

  float r[32];
  int myorig = -1;
  float mydiag = 1.f;
  bool act = (t < m);
  if (act) {
    myorig = rmk[j0 + t];
    const float* src = Mk + (size_t)myorig * N_ + j0;
#pragma unroll
    for (int c4 = 0; c4 < 8; ++c4) *(float4*)&r[c4 * 4] = *(const float4*)(src + c4 * 4);
  }

#pragma unroll
  for (int jj = 0; jj < 32; ++jj) {
    // ---- phase 1: per-wave argmax of |r[jj]| over t in [jj, m) ----
    float bv = (act && t >= jj) ? fabsf(r[jj]) : -1.f;
    int bi = t;
#pragma unroll
    for (int off = 32; off; off >>= 1) {
      float ov = __shfl_xor(bv, off);
      int oi = __shfl_xor(bi, off);
      if (ov > bv) { bv = ov; bi = oi; }
    }
    if (lane == 0) { candv[wid] = bv; candi[wid] = bi; }
    __syncthreads();
    // ---- phase 2: wave 0 reduces the <=16 wave candidates ----
    if (t < 64) {
      float cv = (lane < nw) ? candv[lane] : -1.f;
      int ci = (lane < nw) ? candi[lane] : 0;
#pragma unroll
      for (int off = 8; off; off >>= 1) {
        float ov = __shfl_down(cv, off, 16);
        int oi = __shfl_down(ci, off, 16);
        if (ov > cv) { cv = ov; ci = oi; }
      }
      if (lane == 0) spiv = ci;
    }
    __syncthreads();
    int p = spiv;
    // ---- phase 3: stage pivot row (and displaced row jj if swapping) ----
    if (t == p) {
#pragma unroll
      for (int c4 = 0; c4 < 8; ++c4) *(float4*)&bufP[c4 * 4] = *(const float4*)&r[c4 * 4];
      origP = myorig;
    }
    if (p != jj && t == jj) {
#pragma unroll
      for (int c4 = 0; c4 < 8; ++c4) *(float4*)&bufJ[c4 * 4] = *(const float4*)&r[c4 * 4];
      origJ = myorig;
    }
    __syncthreads();
    // ---- phase 4: adopt swapped rows; broadcast pivot row; rank-1 update ----
    float pr[32];
#pragma unroll
    for (int c4 = 0; c4 < 8; ++c4) *(float4*)&pr[c4 * 4] = *(const float4*)&bufP[c4 * 4];
    if (p != jj) {
      if (t == jj) {
#pragma unroll
        for (int c = 0; c < 32; ++c) r[c] = pr[c];
        myorig = origP;
      } else if (t == p) {
#pragma unroll
        for (int c4 = 0; c4 < 8; ++c4) *(float4*)&r[c4 * 4] = *(const float4*)&bufJ[c4 * 4];
        myorig = origJ;
      }
    }
    float pv = pr[jj];
    if (t == jj) mydiag = pv;
    float sinv = 1.0f / pv;
    if (act && t > jj) {
      float mult = r[jj] * sinv;
      r[jj] = mult;
#pragma unroll
      for (int c = jj + 1; c < 32; ++c) r[c] -= mult * pr[c];
    }
    // no barrier needed here: next step's phase-1/2 barriers fence bufP/bufJ/spiv reuse
  }

  // ---- logdet from saved diagonals (threads 0..31 are wave 0) ----
  if (t < 32) {
    float lv = logf(fabsf(mydiag));
#pragma unroll
    for (int off = 16; off; off >>= 1) lv += __shfl_down(lv, off, 32);
    if (t == 0) logdet[k] += lv;
  }
  // ---- export L/U panel (pivoted order, dense) + rowmap writeback ----
  if (act) {
    float* dst = Mk + (size_t)(j0 + t) * N_ + j0;
#pragma unroll
    for (int c4 = 0; c4 < 8; ++c4) *(float4*)(dst + c4 * 4) = *(const float4*)&r[c4 * 4];
    rmk[j0 + t] = myorig;
  }
}

// ---------------- fused TRSM + trailing GEMM update, 128x128 C tile ----------------
__global__ __launch_bounds__(256) void updatek(float* __restrict__ M, const int* __restrict__ rowmap, int j0) {
  int k = blockIdx.z;
  int mprime = N_ - j0 - 32;
  int r0 = blockIdx.y << 7;
  int c0 = blockIdx.x << 7;
  float* Mk = M + ((size_t)k << 20);
  const int* rmk = rowmap + (k << 10);
  __shared__ float l11[32 * 36];
  __shared__ float LtT[32 * 132];
  __shared__ float Ut[32 * 132];
  __shared__ int rowL[128];
  __shared__ int prU[32];
  int tid = threadIdx.x;

  if (tid < 128) rowL[tid] = (r0 + tid < mprime) ? rmk[j0 + 32 + r0 + tid] : -1;
  else if (tid < 160) prU[tid - 128] = rmk[j0 + (tid - 128)];
  {
    int rr = tid >> 3, q = (tid & 7) << 2;
    *(float4*)&l11[rr * 36 + q] = *(const float4*)(Mk + (size_t)(j0 + rr) * N_ + j0 + q);
  }
  for (int x = tid; x < 1024; x += 256) {
    int i = x >> 3, q = (x & 7) << 2;
    float4 v = {0.f, 0.f, 0.f, 0.f};
    if (r0 + i < mprime) v = *(const float4*)(Mk + (size_t)(j0 + 32 + r0 + i) * N_ + j0 + q);
    LtT[(q + 0) * 132 + i] = v.x;
    LtT[(q + 1) * 132 + i] = v.y;
    LtT[(q + 2) * 132 + i] = v.z;
    LtT[(q + 3) * 132 + i] = v.w;
  }
  __syncthreads();

  // TRSM: threads 0..127 each own one column of the 32x128 U12 tile
  if (tid < 128) {
    int c = c0 + tid;
    bool ok = (c < mprime);
    float u[32];
#pragma unroll
    for (int rr = 0; rr < 32; ++rr) {
      float av = ok ? Mk[(size_t)prU[rr] * N_ + j0 + 32 + c] : 0.f;
#pragma unroll
      for (int t = 0; t < rr; ++t) av -= l11[rr * 36 + t] * u[t];
      u[rr] = av;
      Ut[rr * 132 + tid] = av;
    }
  }
  __syncthreads();

  // GEMM: 128x128 tile, 8x8 per thread in 2x2 blocks of 4x4
  int tx = tid & 15, ty = tid >> 4;
  float4 acc[2][2][4];
#pragma unroll
  for (int a = 0; a < 2; ++a)
#pragma unroll
    for (int b = 0; b < 2; ++b)
#pragma unroll
      for (int r = 0; r < 4; ++r) acc[a][b][r] = make_float4(0.f, 0.f, 0.f, 0.f);

#pragma unroll 8
  for (int t = 0; t < 32; ++t) {
    float4 aL = *(const float4*)&LtT[t * 132 + (ty << 2)];
    float4 aH = *(const float4*)&LtT[t * 132 + (ty << 2) + 64];
    float4 bL = *(const float4*)&Ut[t * 132 + (tx << 2)];
    float4 bH = *(const float4*)&Ut[t * 132 + (tx << 2) + 64];
#define FMA4(dst, s, b4) dst.x += (s) * b4.x; dst.y += (s) * b4.y; dst.z += (s) * b4.z; dst.w += (s) * b4.w;
    FMA4(acc[0][0][0], aL.x, bL) FMA4(acc[0][0][1], aL.y, bL) FMA4(acc[0][0][2], aL.z, bL) FMA4(acc[0][0][3], aL.w, bL)
    FMA4(acc[0][1][0], aL.x, bH) FMA4(acc[0][1][1], aL.y, bH) FMA4(acc[0][1][2], aL.z, bH) FMA4(acc[0][1][3], aL.w, bH)
    FMA4(acc[1][0][0], aH.x, bL) FMA4(acc[1][0][1], aH.y, bL) FMA4(acc[1][0][2], aH.z, bL) FMA4(acc[1][0][3], aH.w, bL)
    FMA4(acc[1][1][0], aH.x, bH) FMA4(acc[1][1][1], aH.y, bH) FMA4(acc[1][1][2], aH.z, bH) FMA4(acc[1][1][3], aH.w, bH)
#undef FMA4
  }

#pragma unroll
  for (int ri = 0; ri < 2; ++ri)
#pragma unroll
    for (int r = 0; r < 4; ++r) {
      int lr = (ty << 2) + r + (ri << 6);
      int pr = rowL[lr];
      if (pr < 0) continue;
      float* rowp = Mk + (size_t)pr * N_ + j0 + 32 + c0;
#pragma unroll
      for (int ci = 0; ci < 2; ++ci) {
        int lc = (tx << 2) + (ci << 6);
        if (c0 + lc < mprime) {
          float4* p = (float4*)(rowp + lc);
          float4 cur = *p;
          cur.x -= acc[ri][ci][r].x;
          cur.y -= acc[ri][ci][r].y;
          cur.z -= acc[ri][ci][r].z;
          cur.w -= acc[ri][ci][r].w;
          *p = cur;
        }
      }
    }
}

// ---------------- final: cross term, lle, softmax ----------------
__global__ __launch_bounds__(256) void finalk(const float* __restrict__ X, const float* __restrict__ rbuf,
                                              const float* __restrict__ cterm, const float* __restrict__ logdet,
                                              const float* __restrict__ Qp, float* __restrict__ out) {
  int b = blockIdx.x;
  __shared__ float Xs[1024];
  __shared__ float lleS[32];
  int tid = threadIdx.x, wave = tid >> 6, lane = tid & 63;
  for (int i = tid; i < 1024; i += 256) Xs[i] = X[(size_t)b * 1024 + i];
  __syncthreads();
#pragma unroll
  for (int kk = 0; kk < 8; ++kk) {
    int k = wave + (kk << 2);
    const float* rk = rbuf + (size_t)k * 1024;
    float acc = 0.f;
#pragma unroll
    for (int ch = 0; ch < 4; ++ch) {
      int e4 = (ch * 64 + lane) << 2;
      const float4 rv = *(const float4*)(rk + e4);
      const float4 xv = *(const float4*)&Xs[e4];
      acc += rv.x * xv.x + rv.y * xv.y + rv.z * xv.z + rv.w * xv.w;
    }
    for (int off = 32; off; off >>= 1) acc += __shfl_xor(acc, off);
    if (lane == 0) {
      float Qv = 0.f;
#pragma unroll
      for (int g = 0; g < 4; ++g) Qv += Qp[((size_t)(g * B_ + b) << 5) + k];
      float P1 = Qv - 2.f * acc + cterm[k];
      lleS[k] = -0.5f * P1 + logdet[k];
    }
  }
  __syncthreads();
  if (wave == 0) {
    float v = lleS[lane & 31];
    float mx = v;
    for (int off = 16; off; off >>= 1) mx = fmaxf(mx, __shfl_xor(mx, off));
    float e = expf(v - mx);
    float s = e;
    for (int off = 16; off; off >>= 1) s += __shfl_xor(s, off);
    if (lane < 32) out[b * 32 + lane] = e / s;
  }
}

extern "C" void kernel_launch(void* const* d_in, const int* in_sizes, int n_in,
                              void* d_out, int out_size, void* d_ws, size_t ws_size,
                              hipStream_t stream) {
  const float* X  = (const float*)d_in[0];
  const float* mu = (const float*)d_in[1];
  const float* A  = (const float*)d_in[2];
  float* out = (float*)d_out;
  float* ws  = (float*)d_ws;

  if (ws_size < 134742272ull) {
    hipMemsetAsync(d_out, 0, (size_t)out_size * sizeof(float), stream);
    return;
  }

  float* M      = ws;                        // 33554432 floats (128 MB)
  int*   rowmap = (int*)(ws + 33554432);     // 32768 ints
  float* logdet = ws + 33587200;             // 32
  float* rbuf   = ws + 33587232;             // 32768
  float* cterm  = ws + 33620000;             // 32
  float* Qp     = ws + 33620032;             // 65536

  initk<<<dim3(128), dim3(256), 0, stream>>>(rowmap, logdet);
  buildM<<<dim3(32768), dim3(256), 0, stream>>>(A, M);
  prepk<<<dim3(32), dim3(256), 0, stream>>>(A, mu, rbuf, cterm);
  qkern<<<dim3(4, 128), dim3(256), 0, stream>>>(X, A, Qp);

  for (int s = 0; s < 32; ++s) {
    int j0 = s * 32;
    int m = N_ - j0;
    int bt = ((m + 63) >> 6) << 6;           // threads = rows, rounded to wave
    panelk<<<dim3(32), dim3(bt), 0, stream>>>(M, rowmap, logdet, j0);
    int mprime = m - 32;
    if (mprime > 0) {
      int mt = (mprime + 127) >> 7;
      updatek<<<dim3(mt, mt, 32), dim3(256), 0, stream>>>(M, rowmap, j0);
    }
  }

  finalk<<<dim3(512), dim3(256), 0, stream>>>(X, rbuf, cterm, logdet, Qp, out);
}